// Round 6
// baseline (95.436 us; speedup 1.0000x reference)
//
#include <hip/hip_runtime.h>

#define R_    116
#define DIN_  116
#define H_    256

typedef float  f32x4  __attribute__((ext_vector_type(4)));
typedef short  short8 __attribute__((ext_vector_type(8)));
typedef int    int4v  __attribute__((ext_vector_type(4)));
typedef int    int2v  __attribute__((ext_vector_type(2)));

// ---- LDS layout (bytes), total exactly 160 KiB. 16B-block XOR swizzle per row.
#define AT_OFF   0        // At [128 c][128 r] bf16 pitch 256B : bb=(r>>3)^(c&7); At[c][r]=max(m[r][c],0)+(r==c)
#define X_OFF    32768    // X  [128 r][128 k] bf16 pitch 256B : bb=(k>>3)^(r&7); zero-padded
#define XS_OFF   65536    // XS [128 f][128 r] bf16 pitch 256B : bb=(r>>3)^(f&7); also temp dinv / final red
#define H1_OFF   98304    // H1 [128 c][256 f] bf16 pitch 512B : bb=(f>>3)^(c&7)
#define LDS_SIZE 163840

__device__ __forceinline__ short f2bf(float f) {
  union { float f; unsigned u; } x; x.f = f;
  unsigned r = x.u + 0x7fffu + ((x.u >> 16) & 1u);
  return (short)(r >> 16);
}
__device__ __forceinline__ float bf2f(short s) {
  union { unsigned u; float f; } x;
  x.u = ((unsigned)(unsigned short)s) << 16;
  return x.f;
}
__device__ __forceinline__ unsigned pack2(float lo, float hi) {
  return (unsigned)(unsigned short)f2bf(lo) | ((unsigned)(unsigned short)f2bf(hi) << 16);
}

// Pre-transpose weights to bf16 Wt[f][k], zero-padded K (layer 1).
__global__ void __launch_bounds__(256) wt_setup(const float* __restrict__ W1,
                                                const float* __restrict__ W2,
                                                short* __restrict__ W1t,
                                                short* __restrict__ W2t) {
  int idx = blockIdx.x * 256 + threadIdx.x;      // 384 blocks
  if (idx < 32768) {                             // W1t [256][128]
    int f = idx >> 7, k = idx & 127;
    float v = (k < DIN_) ? W1[k * H_ + f] : 0.f;
    W1t[idx] = f2bf(v);
  } else {                                       // W2t [256][256]
    int j = idx - 32768;
    int f = j >> 8, k = j & 255;
    W2t[j] = f2bf(W2[k * H_ + f]);
  }
}

__global__ void __launch_bounds__(512, 2) gnn_fused(
    const float* __restrict__ mM, const float* __restrict__ nf,
    const float* __restrict__ b1, const float* __restrict__ b2,
    const float* __restrict__ Wc, const float* __restrict__ bc,
    const short* __restrict__ W1t, const short* __restrict__ W2t,
    float* __restrict__ out)
{
  extern __shared__ char smem[];
  const int b    = blockIdx.x;
  const int tid  = threadIdx.x;
  const int lane = tid & 63;
  const int w    = tid >> 6;     // 0..7 : which 16-col f group
  const int i16  = lane & 15;
  const int q    = lane >> 4;

  // ---- zero At + X (64KB; covers all padding) ----
  for (int t = tid; t < 65536 / 16; t += 512)
    ((int4v*)smem)[t] = (int4v){0, 0, 0, 0};
  __syncthreads();

  // ---- fill At (transposed, relu, +1 diag) and X (bf16), coalesced f32x4 reads ----
  {
    const float* mB = mM + (size_t)b * (R_ * R_);
    const float* xB = nf + (size_t)b * (R_ * DIN_);
    for (int t4 = tid; t4 < (R_ * R_) / 4; t4 += 512) {
      f32x4 v4 = ((const f32x4*)mB)[t4];
      f32x4 x4 = ((const f32x4*)xB)[t4];
      int i0 = t4 * 4;
      int r = i0 / R_, c0 = i0 - r * R_;          // c0 % 4 == 0; row never splits (116%4==0)
#pragma unroll
      for (int e = 0; e < 4; ++e) {               // At: rows differ -> 4 scalar stores
        int c = c0 + e;
        float v = v4[e];
        v = v > 0.f ? v : 0.f;
        if (r == c) v += 1.f;
        int ba = (r >> 3) ^ (c & 7);
        *(short*)(smem + AT_OFF + c * 256 + ba * 16 + (r & 7) * 2) = f2bf(v);
      }
      {                                           // X: same row -> one 8B store
        int bx = (c0 >> 3) ^ (r & 7);
        int2v px;
        px[0] = (int)pack2(x4[0], x4[1]);
        px[1] = (int)pack2(x4[2], x4[3]);
        *(int2v*)(smem + X_OFF + r * 256 + bx * 16 + (c0 & 7) * 2) = px;
      }
    }
  }
  __syncthreads();

  // ---- deg/dinv: 4 threads per row -> temp buffer in the (not-yet-used) XS slot ----
  {
    float* dinvp = (float*)(smem + XS_OFF);
    int row = tid >> 2, part = tid & 3;
    float s = 0.f;
#pragma unroll
    for (int j = 0; j < 4; ++j) {
      int bb = (part * 4 + j) ^ (row & 7);
      short8 v = *(const short8*)(smem + AT_OFF + row * 256 + bb * 16);
#pragma unroll
      for (int e = 0; e < 8; ++e) s += bf2f(v[e]);
    }
    s += __shfl_xor(s, 1);
    s += __shfl_xor(s, 2);
    if (part == 0) dinvp[row] = (row < R_) ? rsqrtf(s) : 0.f;
  }
  __syncthreads();

  // dinv register-resident: dvr = row map (r = t*16 + q*4 + e), dvc = col map (c = t*16 + i16)
  f32x4 dvr[8];
  float dvc[8];
#pragma unroll
  for (int t = 0; t < 8; ++t) {
    dvr[t] = *(const f32x4*)((const float*)(smem + XS_OFF) + t * 16 + q * 4);
    dvc[t] = ((const float*)(smem + XS_OFF))[t * 16 + i16];
  }
  __syncthreads();   // all dinv reads done before XS gets overwritten

  // ---- At fragments register-resident (used 4x: 2 layers x 2 halves) ----
  short8 atreg[8][4];
#pragma unroll
  for (int ct = 0; ct < 8; ++ct) {
#pragma unroll
    for (int ks = 0; ks < 4; ++ks) {
      int bb = (ks * 4 + q) ^ (i16 & 7);
      atreg[ct][ks] = *(const short8*)(smem + AT_OFF + (ct * 16 + i16) * 256 + bb * 16);
    }
  }

  const int fb = w * 16 + i16;
  float ps0 = 0.f, ps1 = 0.f;

  // ================= Layer 1 =================
#pragma unroll 1
  for (int hf = 0; hf < 2; ++hf) {
    const int f = hf * 128 + fb;
    // ---- phase A: xw = X @ W1 for this wave's 16 f-cols, all 128 rows ----
    f32x4 acc[8];
#pragma unroll
    for (int mt = 0; mt < 8; ++mt) acc[mt] = (f32x4){0.f, 0.f, 0.f, 0.f};
#pragma unroll
    for (int ks = 0; ks < 4; ++ks) {
      short8 wf = *(const short8*)(W1t + (size_t)f * 128 + ks * 32 + q * 8);
#pragma unroll
      for (int mt = 0; mt < 8; ++mt) {
        int bb = (ks * 4 + q) ^ (i16 & 7);
        short8 af = *(const short8*)(smem + X_OFF + (mt * 16 + i16) * 256 + bb * 16);
        acc[mt] = __builtin_amdgcn_mfma_f32_16x16x32_bf16(af, wf, acc[mt], 0, 0, 0);
      }
    }
    // scale by dinv[r], write xs -> XS[f][r] (8B packed stores)
#pragma unroll
    for (int mt = 0; mt < 8; ++mt) {
      int r0 = mt * 16 + q * 4;
      int2v pk;
      pk[0] = (int)pack2(acc[mt][0] * dvr[mt][0], acc[mt][1] * dvr[mt][1]);
      pk[1] = (int)pack2(acc[mt][2] * dvr[mt][2], acc[mt][3] * dvr[mt][3]);
      int bb = (r0 >> 3) ^ (i16 & 7);          // f&7 == i16&7
      *(int2v*)(smem + XS_OFF + fb * 256 + bb * 16 + (r0 & 7) * 2) = pk;
    }
    __syncthreads();

    // ---- phase B (SWAPPED): D[f][c] = xs @ At^T -> 4 contiguous f per lane ----
    f32x4 acc2[8];
#pragma unroll
    for (int nt = 0; nt < 8; ++nt) acc2[nt] = (f32x4){0.f, 0.f, 0.f, 0.f};
#pragma unroll
    for (int ks = 0; ks < 4; ++ks) {
      int bb = (ks * 4 + q) ^ (i16 & 7);
      short8 ax = *(const short8*)(smem + XS_OFF + fb * 256 + bb * 16);
#pragma unroll
      for (int nt = 0; nt < 8; ++nt)
        acc2[nt] = __builtin_amdgcn_mfma_f32_16x16x32_bf16(ax, atreg[nt][ks], acc2[nt], 0, 0, 0);
    }
    // epilogue: h1 = leaky(dinv[c]*agg + b1[f]) -> H1[c][f], 8B packed (4 contig f)
    {
      const int f0 = hf * 128 + w * 16 + q * 4;
      f32x4 b1v = *(const f32x4*)(b1 + f0);
#pragma unroll
      for (int nt = 0; nt < 8; ++nt) {
        int c = nt * 16 + i16;
        float dv = dvc[nt];
        float h0 = dv * acc2[nt][0] + b1v[0]; h0 = h0 > 0.f ? h0 : 0.2f * h0;
        float h1 = dv * acc2[nt][1] + b1v[1]; h1 = h1 > 0.f ? h1 : 0.2f * h1;
        float h2 = dv * acc2[nt][2] + b1v[2]; h2 = h2 > 0.f ? h2 : 0.2f * h2;
        float h3 = dv * acc2[nt][3] + b1v[3]; h3 = h3 > 0.f ? h3 : 0.2f * h3;
        int bb = (f0 >> 3) ^ (c & 7);
        int2v pk;
        pk[0] = (int)pack2(h0, h1);
        pk[1] = (int)pack2(h2, h3);
        *(int2v*)(smem + H1_OFF + c * 512 + bb * 16 + (q & 1) * 8) = pk;
      }
    }
    __syncthreads();   // XS consumed + H1 half written
  }

  // ================= Layer 2 =================
#pragma unroll 1
  for (int hf = 0; hf < 2; ++hf) {
    const int f = hf * 128 + fb;
    // ---- phase A: xw2 = H1 @ W2 (K=256) ----
    f32x4 acc[8];
#pragma unroll
    for (int mt = 0; mt < 8; ++mt) acc[mt] = (f32x4){0.f, 0.f, 0.f, 0.f};
#pragma unroll
    for (int ks = 0; ks < 8; ++ks) {
      short8 wf = *(const short8*)(W2t + (size_t)f * 256 + ks * 32 + q * 8);
#pragma unroll
      for (int mt = 0; mt < 8; ++mt) {
        int bb = (ks * 4 + q) ^ (i16 & 7);
        short8 af = *(const short8*)(smem + H1_OFF + (mt * 16 + i16) * 512 + bb * 16);
        acc[mt] = __builtin_amdgcn_mfma_f32_16x16x32_bf16(af, wf, acc[mt], 0, 0, 0);
      }
    }
#pragma unroll
    for (int mt = 0; mt < 8; ++mt) {
      int r0 = mt * 16 + q * 4;
      int2v pk;
      pk[0] = (int)pack2(acc[mt][0] * dvr[mt][0], acc[mt][1] * dvr[mt][1]);
      pk[1] = (int)pack2(acc[mt][2] * dvr[mt][2], acc[mt][3] * dvr[mt][3]);
      int bb = (r0 >> 3) ^ (i16 & 7);
      *(int2v*)(smem + XS_OFF + fb * 256 + bb * 16 + (r0 & 7) * 2) = pk;
    }
    __syncthreads();

    // ---- phase B (SWAPPED) ----
    f32x4 acc2[8];
#pragma unroll
    for (int nt = 0; nt < 8; ++nt) acc2[nt] = (f32x4){0.f, 0.f, 0.f, 0.f};
#pragma unroll
    for (int ks = 0; ks < 4; ++ks) {
      int bb = (ks * 4 + q) ^ (i16 & 7);
      short8 ax = *(const short8*)(smem + XS_OFF + fb * 256 + bb * 16);
#pragma unroll
      for (int nt = 0; nt < 8; ++nt)
        acc2[nt] = __builtin_amdgcn_mfma_f32_16x16x32_bf16(ax, atreg[nt][ks], acc2[nt], 0, 0, 0);
    }
    // epilogue: h2 -> classifier partial dot, vectorized Wc reads (4 contig f)
    {
      const int f0 = hf * 128 + w * 16 + q * 4;
      f32x4 b2v = *(const f32x4*)(b2 + f0);
#pragma unroll
      for (int nt = 0; nt < 8; ++nt) {
        int c = nt * 16 + i16;
        if (c < R_) {
          float dv = dvc[nt];
          float h0 = dv * acc2[nt][0] + b2v[0]; h0 = h0 > 0.f ? h0 : 0.2f * h0;
          float h1 = dv * acc2[nt][1] + b2v[1]; h1 = h1 > 0.f ? h1 : 0.2f * h1;
          float h2 = dv * acc2[nt][2] + b2v[2]; h2 = h2 > 0.f ? h2 : 0.2f * h2;
          float h3 = dv * acc2[nt][3] + b2v[3]; h3 = h3 > 0.f ? h3 : 0.2f * h3;
          f32x4 wc0 = *(const f32x4*)(Wc + (size_t)c * H_ + f0);
          f32x4 wc1 = *(const f32x4*)(Wc + (size_t)(H_ * R_) + (size_t)c * H_ + f0);
          ps0 += h0 * wc0[0] + h1 * wc0[1] + h2 * wc0[2] + h3 * wc0[3];
          ps1 += h0 * wc1[0] + h1 * wc1[1] + h2 * wc1[2] + h3 * wc1[3];
        }
      }
    }
    __syncthreads();   // XS consumed (and, after hf=1, everything done)
  }

  // ---- classifier reduction (reuse XS slot; all XS reads are behind the barrier) ----
#pragma unroll
  for (int off = 32; off; off >>= 1) {
    ps0 += __shfl_xor(ps0, off, 64);
    ps1 += __shfl_xor(ps1, off, 64);
  }
  float* red = (float*)(smem + XS_OFF);
  if (lane == 0) { red[w * 2] = ps0; red[w * 2 + 1] = ps1; }
  __syncthreads();
  if (tid == 0) {
    float s0 = 0.f, s1 = 0.f;
#pragma unroll
    for (int i = 0; i < 8; ++i) { s0 += red[i * 2]; s1 += red[i * 2 + 1]; }
    out[b * 2 + 0] = s0 + bc[0];
    out[b * 2 + 1] = s1 + bc[1];
  }
}

extern "C" void kernel_launch(void* const* d_in, const int* in_sizes, int n_in,
                              void* d_out, int out_size, void* d_ws, size_t ws_size,
                              hipStream_t stream) {
  const float* mM = (const float*)d_in[0];
  const float* nf = (const float*)d_in[1];
  const float* W1 = (const float*)d_in[2];
  const float* b1 = (const float*)d_in[3];
  const float* W2 = (const float*)d_in[4];
  const float* b2 = (const float*)d_in[5];
  const float* Wc = (const float*)d_in[6];
  const float* bc = (const float*)d_in[7];
  float* out = (float*)d_out;

  short* W1t = (short*)d_ws;            // 32768 bf16
  short* W2t = W1t + 32768;             // 65536 bf16

  wt_setup<<<384, 256, 0, stream>>>(W1, W2, W1t, W2t);

  hipFuncSetAttribute((const void*)gnn_fused,
                      hipFuncAttributeMaxDynamicSharedMemorySize, LDS_SIZE);
  gnn_fused<<<512, 512, LDS_SIZE, stream>>>(mM, nf, b1, b2, Wc, bc, W1t, W2t, out);
}

// Round 7
// 67.459 us; speedup vs baseline: 1.4147x; 1.4147x over previous
//
#include <hip/hip_runtime.h>

#define R_    116
#define DIN_  116
#define H_    256

typedef float  f32x4  __attribute__((ext_vector_type(4)));
typedef short  short8 __attribute__((ext_vector_type(8)));
typedef int    int4v  __attribute__((ext_vector_type(4)));
typedef int    int2v  __attribute__((ext_vector_type(2)));

// ---- LDS layout (bytes), total exactly 160 KiB. 16B-block XOR swizzle per row.
#define AT_OFF   0        // At [128 c][128 r] bf16 pitch 256B : bb=(r>>3)^(c&7); At[c][r]=max(m[r][c],0)+(r==c)
#define X_OFF    32768    // X  [128 r][128 k] bf16 pitch 256B : bb=(k>>3)^(r&7); zero-padded
#define XS_OFF   65536    // XS [128 f][128 r] bf16 pitch 256B : bb=(r>>3)^(f&7); also temp dinv / final red
#define H1_OFF   98304    // H1 [128 c][256 f] bf16 pitch 512B : bb=(f>>3)^(c&7)
#define LDS_SIZE 163840

__device__ __forceinline__ short f2bf(float f) {
  union { float f; unsigned u; } x; x.f = f;
  unsigned r = x.u + 0x7fffu + ((x.u >> 16) & 1u);
  return (short)(r >> 16);
}
__device__ __forceinline__ float bf2f(short s) {
  union { unsigned u; float f; } x;
  x.u = ((unsigned)(unsigned short)s) << 16;
  return x.f;
}
__device__ __forceinline__ unsigned pack2(float lo, float hi) {
  return (unsigned)(unsigned short)f2bf(lo) | ((unsigned)(unsigned short)f2bf(hi) << 16);
}

// Pre-transpose weights to bf16 Wt[f][k], zero-padded K (layer 1).
__global__ void __launch_bounds__(256) wt_setup(const float* __restrict__ W1,
                                                const float* __restrict__ W2,
                                                short* __restrict__ W1t,
                                                short* __restrict__ W2t) {
  int idx = blockIdx.x * 256 + threadIdx.x;      // 384 blocks
  if (idx < 32768) {                             // W1t [256][128]
    int f = idx >> 7, k = idx & 127;
    float v = (k < DIN_) ? W1[k * H_ + f] : 0.f;
    W1t[idx] = f2bf(v);
  } else {                                       // W2t [256][256]
    int j = idx - 32768;
    int f = j >> 8, k = j & 255;
    W2t[j] = f2bf(W2[k * H_ + f]);
  }
}

__global__ void __launch_bounds__(512, 2) gnn_fused(
    const float* __restrict__ mM, const float* __restrict__ nf,
    const float* __restrict__ b1, const float* __restrict__ b2,
    const float* __restrict__ Wc, const float* __restrict__ bc,
    const short* __restrict__ W1t, const short* __restrict__ W2t,
    float* __restrict__ out)
{
  extern __shared__ char smem[];
  const int b    = blockIdx.x;
  const int tid  = threadIdx.x;
  const int lane = tid & 63;
  const int w    = tid >> 6;     // 0..7 : which 16-col f group
  const int i16  = lane & 15;
  const int q    = lane >> 4;

  // ---- zero At + X (64KB; covers all padding) ----
  for (int t = tid; t < 65536 / 16; t += 512)
    ((int4v*)smem)[t] = (int4v){0, 0, 0, 0};
  __syncthreads();

  // ---- fill At (transposed, relu, +1 diag) and X (bf16), coalesced f32x4 reads ----
  {
    const float* mB = mM + (size_t)b * (R_ * R_);
    const float* xB = nf + (size_t)b * (R_ * DIN_);
    for (int t4 = tid; t4 < (R_ * R_) / 4; t4 += 512) {
      f32x4 v4 = ((const f32x4*)mB)[t4];
      f32x4 x4 = ((const f32x4*)xB)[t4];
      int i0 = t4 * 4;
      int r = i0 / R_, c0 = i0 - r * R_;          // c0 % 4 == 0; row never splits (116%4==0)
#pragma unroll
      for (int e = 0; e < 4; ++e) {               // At: rows differ -> 4 scalar stores
        int c = c0 + e;
        float v = v4[e];
        v = v > 0.f ? v : 0.f;
        if (r == c) v += 1.f;
        int ba = (r >> 3) ^ (c & 7);
        *(short*)(smem + AT_OFF + c * 256 + ba * 16 + (r & 7) * 2) = f2bf(v);
      }
      {                                           // X: same row -> one 8B store
        int bx = (c0 >> 3) ^ (r & 7);
        int2v px;
        px[0] = (int)pack2(x4[0], x4[1]);
        px[1] = (int)pack2(x4[2], x4[3]);
        *(int2v*)(smem + X_OFF + r * 256 + bx * 16 + (c0 & 7) * 2) = px;
      }
    }
  }
  __syncthreads();

  // ---- deg/dinv: 4 threads per row -> temp buffer in the (not-yet-used) XS slot ----
  {
    float* dinvp = (float*)(smem + XS_OFF);
    int row = tid >> 2, part = tid & 3;
    float s = 0.f;
#pragma unroll
    for (int j = 0; j < 4; ++j) {
      int bb = (part * 4 + j) ^ (row & 7);
      short8 v = *(const short8*)(smem + AT_OFF + row * 256 + bb * 16);
#pragma unroll
      for (int e = 0; e < 8; ++e) s += bf2f(v[e]);
    }
    s += __shfl_xor(s, 1);
    s += __shfl_xor(s, 2);
    if (part == 0) dinvp[row] = (row < R_) ? rsqrtf(s) : 0.f;
  }
  __syncthreads();

  // dinv register-resident: dvr = row map (r = t*16 + q*4 + e), dvc = col map (c = t*16 + i16)
  f32x4 dvr[8];
  float dvc[8];
#pragma unroll
  for (int t = 0; t < 8; ++t) {
    dvr[t] = *(const f32x4*)((const float*)(smem + XS_OFF) + t * 16 + q * 4);
    dvc[t] = ((const float*)(smem + XS_OFF))[t * 16 + i16];
  }
  __syncthreads();   // all dinv reads done before XS gets overwritten

  const int fb = w * 16 + i16;
  float ps0 = 0.f, ps1 = 0.f;

  // ================= Layer 1 =================
#pragma unroll 1
  for (int hf = 0; hf < 2; ++hf) {
    const int f = hf * 128 + fb;
    // ---- phase A: xw = X @ W1 for this wave's 16 f-cols, all 128 rows ----
    f32x4 acc[8];
#pragma unroll
    for (int mt = 0; mt < 8; ++mt) acc[mt] = (f32x4){0.f, 0.f, 0.f, 0.f};
#pragma unroll
    for (int ks = 0; ks < 4; ++ks) {
      short8 wf = *(const short8*)(W1t + (size_t)f * 128 + ks * 32 + q * 8);
#pragma unroll
      for (int mt = 0; mt < 8; ++mt) {
        int bb = (ks * 4 + q) ^ (i16 & 7);
        short8 af = *(const short8*)(smem + X_OFF + (mt * 16 + i16) * 256 + bb * 16);
        acc[mt] = __builtin_amdgcn_mfma_f32_16x16x32_bf16(af, wf, acc[mt], 0, 0, 0);
      }
    }
    // scale by dinv[r], write xs -> XS[f][r] (8B packed stores)
#pragma unroll
    for (int mt = 0; mt < 8; ++mt) {
      int r0 = mt * 16 + q * 4;
      int2v pk;
      pk[0] = (int)pack2(acc[mt][0] * dvr[mt][0], acc[mt][1] * dvr[mt][1]);
      pk[1] = (int)pack2(acc[mt][2] * dvr[mt][2], acc[mt][3] * dvr[mt][3]);
      int bb = (r0 >> 3) ^ (i16 & 7);          // f&7 == i16&7
      *(int2v*)(smem + XS_OFF + fb * 256 + bb * 16 + (r0 & 7) * 2) = pk;
    }
    __syncthreads();

    // ---- phase B (SWAPPED operands): D[f][c] -> 4 contiguous f per lane ----
    f32x4 acc2[8];
#pragma unroll
    for (int nt = 0; nt < 8; ++nt) acc2[nt] = (f32x4){0.f, 0.f, 0.f, 0.f};
#pragma unroll
    for (int ks = 0; ks < 4; ++ks) {
      int bb = (ks * 4 + q) ^ (i16 & 7);
      short8 ax = *(const short8*)(smem + XS_OFF + fb * 256 + bb * 16);
#pragma unroll
      for (int nt = 0; nt < 8; ++nt) {
        short8 atf = *(const short8*)(smem + AT_OFF + (nt * 16 + i16) * 256 + bb * 16);
        acc2[nt] = __builtin_amdgcn_mfma_f32_16x16x32_bf16(ax, atf, acc2[nt], 0, 0, 0);
      }
    }
    // epilogue: h1 = leaky(dinv[c]*agg + b1[f]) -> H1[c][f], 8B packed (4 contig f)
    {
      const int f0 = hf * 128 + w * 16 + q * 4;
      f32x4 b1v = *(const f32x4*)(b1 + f0);
#pragma unroll
      for (int nt = 0; nt < 8; ++nt) {
        int c = nt * 16 + i16;
        float dv = dvc[nt];
        float h0 = dv * acc2[nt][0] + b1v[0]; h0 = h0 > 0.f ? h0 : 0.2f * h0;
        float h1 = dv * acc2[nt][1] + b1v[1]; h1 = h1 > 0.f ? h1 : 0.2f * h1;
        float h2 = dv * acc2[nt][2] + b1v[2]; h2 = h2 > 0.f ? h2 : 0.2f * h2;
        float h3 = dv * acc2[nt][3] + b1v[3]; h3 = h3 > 0.f ? h3 : 0.2f * h3;
        int bb = (f0 >> 3) ^ (c & 7);
        int2v pk;
        pk[0] = (int)pack2(h0, h1);
        pk[1] = (int)pack2(h2, h3);
        *(int2v*)(smem + H1_OFF + c * 512 + bb * 16 + (q & 1) * 8) = pk;
      }
    }
    __syncthreads();   // XS consumed + H1 half written
  }

  // ================= Layer 2 =================
#pragma unroll 1
  for (int hf = 0; hf < 2; ++hf) {
    const int f = hf * 128 + fb;
    // ---- phase A: xw2 = H1 @ W2 (K=256) ----
    f32x4 acc[8];
#pragma unroll
    for (int mt = 0; mt < 8; ++mt) acc[mt] = (f32x4){0.f, 0.f, 0.f, 0.f};
#pragma unroll
    for (int ks = 0; ks < 8; ++ks) {
      short8 wf = *(const short8*)(W2t + (size_t)f * 256 + ks * 32 + q * 8);
#pragma unroll
      for (int mt = 0; mt < 8; ++mt) {
        int bb = (ks * 4 + q) ^ (i16 & 7);
        short8 af = *(const short8*)(smem + H1_OFF + (mt * 16 + i16) * 512 + bb * 16);
        acc[mt] = __builtin_amdgcn_mfma_f32_16x16x32_bf16(af, wf, acc[mt], 0, 0, 0);
      }
    }
#pragma unroll
    for (int mt = 0; mt < 8; ++mt) {
      int r0 = mt * 16 + q * 4;
      int2v pk;
      pk[0] = (int)pack2(acc[mt][0] * dvr[mt][0], acc[mt][1] * dvr[mt][1]);
      pk[1] = (int)pack2(acc[mt][2] * dvr[mt][2], acc[mt][3] * dvr[mt][3]);
      int bb = (r0 >> 3) ^ (i16 & 7);
      *(int2v*)(smem + XS_OFF + fb * 256 + bb * 16 + (r0 & 7) * 2) = pk;
    }
    __syncthreads();

    // ---- phase B (SWAPPED operands) ----
    f32x4 acc2[8];
#pragma unroll
    for (int nt = 0; nt < 8; ++nt) acc2[nt] = (f32x4){0.f, 0.f, 0.f, 0.f};
#pragma unroll
    for (int ks = 0; ks < 4; ++ks) {
      int bb = (ks * 4 + q) ^ (i16 & 7);
      short8 ax = *(const short8*)(smem + XS_OFF + fb * 256 + bb * 16);
#pragma unroll
      for (int nt = 0; nt < 8; ++nt) {
        short8 atf = *(const short8*)(smem + AT_OFF + (nt * 16 + i16) * 256 + bb * 16);
        acc2[nt] = __builtin_amdgcn_mfma_f32_16x16x32_bf16(ax, atf, acc2[nt], 0, 0, 0);
      }
    }
    // epilogue: h2 -> classifier partial dot, vectorized Wc reads (4 contig f)
    {
      const int f0 = hf * 128 + w * 16 + q * 4;
      f32x4 b2v = *(const f32x4*)(b2 + f0);
#pragma unroll
      for (int nt = 0; nt < 8; ++nt) {
        int c = nt * 16 + i16;
        if (c < R_) {
          float dv = dvc[nt];
          float h0 = dv * acc2[nt][0] + b2v[0]; h0 = h0 > 0.f ? h0 : 0.2f * h0;
          float h1 = dv * acc2[nt][1] + b2v[1]; h1 = h1 > 0.f ? h1 : 0.2f * h1;
          float h2 = dv * acc2[nt][2] + b2v[2]; h2 = h2 > 0.f ? h2 : 0.2f * h2;
          float h3 = dv * acc2[nt][3] + b2v[3]; h3 = h3 > 0.f ? h3 : 0.2f * h3;
          f32x4 wc0 = *(const f32x4*)(Wc + (size_t)c * H_ + f0);
          f32x4 wc1 = *(const f32x4*)(Wc + (size_t)(H_ * R_) + (size_t)c * H_ + f0);
          ps0 += h0 * wc0[0] + h1 * wc0[1] + h2 * wc0[2] + h3 * wc0[3];
          ps1 += h0 * wc1[0] + h1 * wc1[1] + h2 * wc1[2] + h3 * wc1[3];
        }
      }
    }
    __syncthreads();   // XS consumed (and, after hf=1, everything done)
  }

  // ---- classifier reduction (reuse XS slot; all XS reads are behind the barrier) ----
#pragma unroll
  for (int off = 32; off; off >>= 1) {
    ps0 += __shfl_xor(ps0, off, 64);
    ps1 += __shfl_xor(ps1, off, 64);
  }
  float* red = (float*)(smem + XS_OFF);
  if (lane == 0) { red[w * 2] = ps0; red[w * 2 + 1] = ps1; }
  __syncthreads();
  if (tid == 0) {
    float s0 = 0.f, s1 = 0.f;
#pragma unroll
    for (int i = 0; i < 8; ++i) { s0 += red[i * 2]; s1 += red[i * 2 + 1]; }
    out[b * 2 + 0] = s0 + bc[0];
    out[b * 2 + 1] = s1 + bc[1];
  }
}

extern "C" void kernel_launch(void* const* d_in, const int* in_sizes, int n_in,
                              void* d_out, int out_size, void* d_ws, size_t ws_size,
                              hipStream_t stream) {
  const float* mM = (const float*)d_in[0];
  const float* nf = (const float*)d_in[1];
  const float* W1 = (const float*)d_in[2];
  const float* b1 = (const float*)d_in[3];
  const float* W2 = (const float*)d_in[4];
  const float* b2 = (const float*)d_in[5];
  const float* Wc = (const float*)d_in[6];
  const float* bc = (const float*)d_in[7];
  float* out = (float*)d_out;

  short* W1t = (short*)d_ws;            // 32768 bf16
  short* W2t = W1t + 32768;             // 65536 bf16

  wt_setup<<<384, 256, 0, stream>>>(W1, W2, W1t, W2t);

  hipFuncSetAttribute((const void*)gnn_fused,
                      hipFuncAttributeMaxDynamicSharedMemorySize, LDS_SIZE);
  gnn_fused<<<512, 512, LDS_SIZE, stream>>>(mM, nf, b1, b2, Wc, bc, W1t, W2t, out);
}